// Round 16
// baseline (158.683 us; speedup 1.0000x reference)
//
#include <hip/hip_runtime.h>
#include <math.h>

#define BATCH 256
#define CLS 500
#define T_TEMP_ 10.0f
#define THRESH_ 0.86602540378443864676f
#define NEGV -9.0e15f
#define CAP 16

typedef __attribute__((ext_vector_type(8))) short short8;
typedef __attribute__((ext_vector_type(8))) unsigned short u16x8;
typedef __attribute__((ext_vector_type(4))) unsigned short u16x4;
typedef __attribute__((ext_vector_type(4))) float f32x4;
typedef __attribute__((ext_vector_type(2))) float f32x2;

static __device__ __forceinline__ unsigned short f2bf(float x) {
    unsigned int u = __builtin_bit_cast(unsigned int, x);
    u += 0x7fff + ((u >> 16) & 1);
    return (unsigned short)(u >> 16);
}
static __device__ __forceinline__ float bf2f(unsigned short v) {
    return __builtin_bit_cast(float, (unsigned int)v << 16);
}
static __device__ __forceinline__ float fel(const float4& v, int j) { return (&v.x)[j]; }
static __device__ __forceinline__ u16x8 pack8(const float4& a, const float4& b) {
    u16x8 o;
    o[0] = f2bf(a.x); o[1] = f2bf(a.y); o[2] = f2bf(a.z); o[3] = f2bf(a.w);
    o[4] = f2bf(b.x); o[5] = f2bf(b.y); o[6] = f2bf(b.z); o[7] = f2bf(b.w);
    return o;
}

// =============== N1: mega-GEMM v2 — 3 independent families (r14-verified body) ===============
// bid [0,128):   G: gpart[8][512][256] f32 = split-K8 partials of attrs@attg
// bid [128,160): I: imgH[256][1024] bf16 = imgf@imgw, full K
// bid [160,224): S: asem[512][1024] bf16 = attrs@semw, full K
__global__ __launch_bounds__(256) void mega_gemm(
    const float* __restrict__ attrs, const float* __restrict__ attg,
    const float* __restrict__ imgf, const float* __restrict__ imgw,
    const float* __restrict__ semw,
    float* __restrict__ gpart, unsigned short* __restrict__ imgH,
    unsigned short* __restrict__ asem)
{
    __shared__ unsigned short As[64][40];
    __shared__ unsigned short Bs[128][40];
    const int t = threadIdx.x;
    const int bid = blockIdx.x;

    const int w = t >> 6, lane = t & 63;
    const int wr = w >> 1, wc = w & 1;
    const int fr = lane & 15, kg = lane >> 4;
    const int as_row = t >> 2, as_kq = t & 3;
    const int bs_nc = (t & 31) * 4, bs_kr = t >> 5;

    const float* A; const float* Bf;
    int ar0, alim, n0, k0, klen, bstride, split = 0;
    if (bid < 128) {
        const int mt = bid >> 4, nt = (bid >> 3) & 1; split = bid & 7;
        A = attrs; alim = CLS; ar0 = mt * 64;
        Bf = attg; bstride = 256; n0 = nt * 128;
        k0 = split * 128; klen = 128;
    } else if (bid < 160) {
        const int idx = bid - 128;
        const int mt = idx >> 3, nt = idx & 7;
        A = imgf; alim = 256; ar0 = mt * 64;
        Bf = imgw; bstride = 1024; n0 = nt * 128;
        k0 = 0; klen = 1024;
    } else {
        const int idx = bid - 160;
        const int mt = idx >> 3, nt = idx & 7;
        A = attrs; alim = CLS; ar0 = mt * 64;
        Bf = semw; bstride = 1024; n0 = nt * 128;
        k0 = 0; klen = 1024;
    }

    f32x4 acc[2][4];
    #pragma unroll
    for (int i = 0; i < 2; ++i)
        #pragma unroll
        for (int j = 0; j < 4; ++j) acc[i][j] = (f32x4){0.f, 0.f, 0.f, 0.f};

    for (int kb = k0; kb < k0 + klen; kb += 32) {
        {   // A stage: f32 -> bf16 (r14-verified)
            const int gr = ar0 + as_row;
            float4 v0 = make_float4(0.f,0.f,0.f,0.f), v1 = v0;
            if (gr < alim) {
                const float* ap = &A[(size_t)gr * 1024 + kb + as_kq * 8];
                v0 = *(const float4*)ap; v1 = *(const float4*)(ap + 4);
            }
            *(u16x8*)&As[as_row][as_kq * 8] = pack8(v0, v1);
        }
        {   // B stage: f32 [K][bstride] -> Bs[n][k] (r14-verified)
            const float* bp = &Bf[(size_t)(kb + bs_kr * 4) * bstride + n0 + bs_nc];
            float4 r0 = *(const float4*)(bp);
            float4 r1 = *(const float4*)(bp + bstride);
            float4 r2 = *(const float4*)(bp + 2 * bstride);
            float4 r3 = *(const float4*)(bp + 3 * bstride);
            #pragma unroll
            for (int j = 0; j < 4; ++j) {
                unsigned int lo = (unsigned int)f2bf(fel(r0, j)) | ((unsigned int)f2bf(fel(r1, j)) << 16);
                unsigned int hi = (unsigned int)f2bf(fel(r2, j)) | ((unsigned int)f2bf(fel(r3, j)) << 16);
                uint2 u2; u2.x = lo; u2.y = hi;
                *(uint2*)&Bs[bs_nc + j][bs_kr * 4] = u2;
            }
        }
        __syncthreads();
        short8 af[2], bfr[4];
        #pragma unroll
        for (int i = 0; i < 2; ++i) af[i] = *(short8*)&As[wr * 32 + i * 16 + fr][kg * 8];
        #pragma unroll
        for (int j = 0; j < 4; ++j) bfr[j] = *(short8*)&Bs[wc * 64 + j * 16 + fr][kg * 8];
        #pragma unroll
        for (int i = 0; i < 2; ++i)
            #pragma unroll
            for (int j = 0; j < 4; ++j)
                acc[i][j] = __builtin_amdgcn_mfma_f32_16x16x32_bf16(af[i], bfr[j], acc[i][j], 0, 0, 0);
        __syncthreads();
    }

    const int orow0 = ar0 + wr * 32, ocol0 = n0 + wc * 64;
    if (bid < 128) {
        float* Gp = gpart + (size_t)split * (512 * 256);
        #pragma unroll
        for (int i = 0; i < 2; ++i) {
            const int r0 = orow0 + i * 16 + kg * 4;
            #pragma unroll
            for (int j = 0; j < 4; ++j) {
                const int cc = ocol0 + j * 16 + fr;
                #pragma unroll
                for (int r = 0; r < 4; ++r)
                    Gp[(size_t)(r0 + r) * 256 + cc] = acc[i][j][r];
            }
        }
    } else {
        unsigned short* Cw = (bid < 160) ? imgH : asem;
        #pragma unroll
        for (int i = 0; i < 2; ++i) {
            const int r0 = orow0 + i * 16 + kg * 4;
            #pragma unroll
            for (int j = 0; j < 4; ++j) {
                const int cc = ocol0 + j * 16 + fr;
                #pragma unroll
                for (int r = 0; r < 4; ++r)
                    Cw[(size_t)(r0 + r) * 1024 + cc] = f2bf(acc[i][j][r]);
            }
        }
    }
}

// =============== N2: reduce 8 partials + row-normalize -> gn bf16 (r14-verified, verbatim) ===============
__global__ __launch_bounds__(256) void reduce_norm_kernel(
    const float* __restrict__ part, unsigned short* __restrict__ gn_bf)
{
    const int c = blockIdx.x, t = threadIdx.x;
    float v = 0.f;
    #pragma unroll
    for (int z = 0; z < 8; ++z) v += part[(size_t)z * (512 * 256) + c * 256 + t];
    float ss = v * v;
    #pragma unroll
    for (int off = 32; off >= 1; off >>= 1) ss += __shfl_down(ss, off);
    __shared__ float red[4];
    const int wave = t >> 6, lane = t & 63;
    if (lane == 0) red[wave] = ss;
    __syncthreads();
    const float tot = red[0] + red[1] + red[2] + red[3];
    const float rn  = 1.f / sqrtf(tot);
    gn_bf[c * 256 + t] = f2bf(v * rn);
}

// =============== N3: sim = gn @ gn^T (r14-verified, verbatim) ===============
__global__ __launch_bounds__(256) void sim_kernel(
    const unsigned short* __restrict__ gn, float* __restrict__ S)
{
    __shared__ unsigned short As[64][40];
    __shared__ unsigned short Bs[128][40];
    const int t  = threadIdx.x;
    const int ar0 = blockIdx.x * 64;
    const int n0  = blockIdx.y * 128;

    const int w = t >> 6, lane = t & 63;
    const int wr = w >> 1, wc = w & 1;
    const int fr = lane & 15, kg = lane >> 4;
    const int a_row = t >> 2, a_k = (t & 3) * 8;
    const int b_row = t >> 1, b_k = (t & 1) * 16;
    const int gra = ar0 + a_row;
    const int grb = n0 + b_row;
    const bool va = gra < CLS;
    const bool vb = grb < CLS;
    const size_t abase = (size_t)gra * 256 + a_k;
    const size_t bbase = (size_t)grb * 256 + b_k;

    u16x8 zz = {0,0,0,0,0,0,0,0};
    u16x8 pa = zz, pb0 = zz, pb1 = zz;
    if (va) pa = *(const u16x8*)&gn[abase];
    if (vb) { pb0 = *(const u16x8*)&gn[bbase]; pb1 = *(const u16x8*)&gn[bbase + 8]; }

    f32x4 acc[2][4];
    #pragma unroll
    for (int i = 0; i < 2; ++i)
        #pragma unroll
        for (int j = 0; j < 4; ++j) acc[i][j] = (f32x4){0.f, 0.f, 0.f, 0.f};

    for (int kb = 0; kb < 256; kb += 32) {
        *(u16x8*)&As[a_row][a_k] = pa;
        *(u16x8*)&Bs[b_row][b_k] = pb0;
        *(u16x8*)&Bs[b_row][b_k + 8] = pb1;
        __syncthreads();

        const int kn = kb + 32;
        if (kn < 256) {
            if (va) pa = *(const u16x8*)&gn[abase + kn];
            if (vb) { pb0 = *(const u16x8*)&gn[bbase + kn]; pb1 = *(const u16x8*)&gn[bbase + kn + 8]; }
        }

        short8 af[2], bfr[4];
        #pragma unroll
        for (int i = 0; i < 2; ++i) af[i] = *(short8*)&As[wr * 32 + i * 16 + fr][kg * 8];
        #pragma unroll
        for (int j = 0; j < 4; ++j) bfr[j] = *(short8*)&Bs[wc * 64 + j * 16 + fr][kg * 8];
        #pragma unroll
        for (int i = 0; i < 2; ++i)
            #pragma unroll
            for (int j = 0; j < 4; ++j)
                acc[i][j] = __builtin_amdgcn_mfma_f32_16x16x32_bf16(af[i], bfr[j], acc[i][j], 0, 0, 0);
        __syncthreads();
    }

    const int orow0 = ar0 + wr * 32, ocol0 = n0 + wc * 64;
    #pragma unroll
    for (int i = 0; i < 2; ++i) {
        const int r0 = orow0 + i * 16 + kg * 4;
        #pragma unroll
        for (int j = 0; j < 4; ++j) {
            const int cc = ocol0 + j * 16 + fr;
            if (cc >= CLS) continue;
            #pragma unroll
            for (int r = 0; r < 4; ++r) {
                const int rr = r0 + r;
                if (rr < CLS) S[(size_t)rr * CLS + cc] = acc[i][j][r];
            }
        }
    }
}

// =============== N4: fused softmax-gather + relu-reduction (1024 blocks) ===============
// grid (4,8,32). Phase 1: r12-validated per-wave softmax + ballot hit-lists (global sim).
// Staging: img from imgH direct; sem gathered from asem (+semb). Phase 2: r14 body.
__global__ __launch_bounds__(256) void fused_sg(
    const float* __restrict__ sim, const unsigned short* __restrict__ imgH,
    const unsigned short* __restrict__ asem, const float* __restrict__ semb,
    const float* __restrict__ fc_w, float* __restrict__ outpart)
{
    __shared__ float imgs[64][36];
    __shared__ float sems[64][36];
    __shared__ float fcs[32];
    __shared__ int   cnt_s[64];
    __shared__ int   hitc2[64][CAP];
    __shared__ float hitw[64][CAP];
    __shared__ float mrow[64];
    __shared__ float invrow[64];

    const int t  = threadIdx.x;
    const int tb = t >> 4, tc = t & 15;
    const int b0 = blockIdx.x * 64, c0 = blockIdx.y * 64;
    const int h0 = blockIdx.z * 32;
    const int w = t >> 6, lane = t & 63;

    if (t < 8) *(float4*)&fcs[t * 4] = *(const float4*)&fc_w[h0 + t * 4];

    // ---- phase 1: softmax weights for rows c0..c0+63 (r12-validated) ----
    for (int i = 0; i < 16; ++i) {
        const int rl = w * 16 + i;
        const int r  = c0 + rl;
        float vals[8];
        float vmax = NEGV;
        if (r < CLS) {
            #pragma unroll
            for (int ch = 0; ch < 8; ++ch) {
                const int c2 = ch * 64 + lane;
                const float d = (c2 < CLS) ? sim[(size_t)r * CLS + c2] : NEGV;
                vals[ch] = d;
                vmax = fmaxf(vmax, (d > THRESH_) ? d : NEGV);
            }
        } else {
            #pragma unroll
            for (int ch = 0; ch < 8; ++ch) vals[ch] = NEGV;
        }
        #pragma unroll
        for (int off = 32; off >= 1; off >>= 1) vmax = fmaxf(vmax, __shfl_down(vmax, off));
        vmax = __shfl(vmax, 0);
        float pvs[8];
        float s = 0.f;
        #pragma unroll
        for (int ch = 0; ch < 8; ++ch) {
            const float pv = (vals[ch] > THRESH_) ? expf(T_TEMP_ * (vals[ch] - vmax)) : 0.f;
            pvs[ch] = pv; s += pv;
        }
        #pragma unroll
        for (int off = 32; off >= 1; off >>= 1) s += __shfl_down(s, off);
        s = __shfl(s, 0);
        const float inv = (r < CLS) ? 1.f / s : 0.f;
        int count = 0;
        #pragma unroll
        for (int ch = 0; ch < 8; ++ch) {
            unsigned long long mk = __ballot(pvs[ch] > 0.f);
            while (mk) {
                const int l = __ffsll((long long)mk) - 1;
                mk &= mk - 1;
                const float wgt = __shfl(pvs[ch], l) * inv;
                if (count < CAP && lane == 0) {
                    hitc2[rl][count] = ch * 64 + l;
                    hitw[rl][count]  = wgt;
                }
                ++count;
            }
        }
        if (lane == 0) { cnt_s[rl] = count; mrow[rl] = vmax; invrow[rl] = inv; }
    }
    __syncthreads();

    // ---- staging: img direct, sem gathered ----
    {
        const int row = t >> 2, col = (t & 3) * 8;
        u16x8 vz = *(const u16x8*)&imgH[(size_t)(b0 + row) * 1024 + h0 + col];
        f32x4 iv0, iv1;
        iv0[0] = bf2f(vz[0]); iv0[1] = bf2f(vz[1]); iv0[2] = bf2f(vz[2]); iv0[3] = bf2f(vz[3]);
        iv1[0] = bf2f(vz[4]); iv1[1] = bf2f(vz[5]); iv1[2] = bf2f(vz[6]); iv1[3] = bf2f(vz[7]);
        *(f32x4*)&imgs[row][col]     = iv0;
        *(f32x4*)&imgs[row][col + 4] = iv1;

        f32x4 sv0 = {0.f,0.f,0.f,0.f}, sv1 = sv0;
        if (c0 + row < CLS) {
            const int n = cnt_s[row];
            if (n <= CAP) {
                for (int k = 0; k < n; ++k) {
                    const int c2 = hitc2[row][k];
                    const float wgt = hitw[row][k];
                    u16x8 hv = *(const u16x8*)&asem[(size_t)c2 * 1024 + h0 + col];
                    sv0[0] += wgt * bf2f(hv[0]); sv0[1] += wgt * bf2f(hv[1]);
                    sv0[2] += wgt * bf2f(hv[2]); sv0[3] += wgt * bf2f(hv[3]);
                    sv1[0] += wgt * bf2f(hv[4]); sv1[1] += wgt * bf2f(hv[5]);
                    sv1[2] += wgt * bf2f(hv[6]); sv1[3] += wgt * bf2f(hv[7]);
                }
            } else {
                // exact slow path (not expected on this data)
                const int r = c0 + row;
                const float mr = mrow[row], ir = invrow[row];
                for (int c2 = 0; c2 < CLS; ++c2) {
                    const float d = sim[(size_t)r * CLS + c2];
                    if (d > THRESH_) {
                        const float wgt = expf(T_TEMP_ * (d - mr)) * ir;
                        u16x8 hv = *(const u16x8*)&asem[(size_t)c2 * 1024 + h0 + col];
                        sv0[0] += wgt * bf2f(hv[0]); sv0[1] += wgt * bf2f(hv[1]);
                        sv0[2] += wgt * bf2f(hv[2]); sv0[3] += wgt * bf2f(hv[3]);
                        sv1[0] += wgt * bf2f(hv[4]); sv1[1] += wgt * bf2f(hv[5]);
                        sv1[2] += wgt * bf2f(hv[6]); sv1[3] += wgt * bf2f(hv[7]);
                    }
                }
            }
            sv0 += *(const f32x4*)&semb[h0 + col];
            sv1 += *(const f32x4*)&semb[h0 + col + 4];
        }
        *(f32x4*)&sems[row][col]     = sv0;
        *(f32x4*)&sems[row][col + 4] = sv1;
    }
    __syncthreads();

    // ---- phase 2: relu-reduce (r14-verified body) ----
    f32x2 acc2[4][4];
    #pragma unroll
    for (int i = 0; i < 4; ++i)
        #pragma unroll
        for (int j = 0; j < 4; ++j) acc2[i][j] = (f32x2){0.f, 0.f};

    #pragma unroll
    for (int h4 = 0; h4 < 8; ++h4) {
        f32x4 ia[4], sa[4];
        #pragma unroll
        for (int i = 0; i < 4; ++i) ia[i] = *(f32x4*)&imgs[tb + 16 * i][h4 * 4];
        #pragma unroll
        for (int j = 0; j < 4; ++j) sa[j] = *(f32x4*)&sems[tc + 16 * j][h4 * 4];
        const f32x4 wv = *(const f32x4*)&fcs[h4 * 4];
        #pragma unroll
        for (int e2 = 0; e2 < 2; ++e2) {
            const f32x2 w2 = {wv[2 * e2], wv[2 * e2 + 1]};
            f32x2 ia2[4], sa2[4];
            #pragma unroll
            for (int i = 0; i < 4; ++i) ia2[i] = (f32x2){ia[i][2 * e2], ia[i][2 * e2 + 1]};
            #pragma unroll
            for (int j = 0; j < 4; ++j) sa2[j] = (f32x2){sa[j][2 * e2], sa[j][2 * e2 + 1]};
            #pragma unroll
            for (int i = 0; i < 4; ++i)
                #pragma unroll
                for (int j = 0; j < 4; ++j) {
                    f32x2 s = ia2[i] + sa2[j];
                    s = __builtin_elementwise_max(s, (f32x2){0.f, 0.f});
                    acc2[i][j] += s * w2;
                }
        }
    }

    const int nh = blockIdx.z;
    #pragma unroll
    for (int i = 0; i < 4; ++i) {
        const int b = b0 + tb + 16 * i;
        #pragma unroll
        for (int j = 0; j < 4; ++j) {
            const int cc = c0 + tc + 16 * j;
            if (cc < CLS)
                outpart[((size_t)nh * BATCH + b) * CLS + cc] = acc2[i][j][0] + acc2[i][j][1];
        }
    }
}

// =============== N5: finalize (32 partials, r14-verified verbatim) ===============
__global__ __launch_bounds__(256) void finalize_kernel(
    const float* __restrict__ partial, const float* __restrict__ fc_b,
    float* __restrict__ out)
{
    const int idx = blockIdx.x * 256 + threadIdx.x;
    if (idx >= BATCH * CLS) return;
    float s = fc_b[0];
    #pragma unroll
    for (int nh = 0; nh < 32; ++nh)
        s += partial[(size_t)nh * (BATCH * CLS) + idx];
    out[idx] = s;
}

extern "C" void kernel_launch(void* const* d_in, const int* in_sizes, int n_in,
                              void* d_out, int out_size, void* d_ws, size_t ws_size,
                              hipStream_t stream)
{
    const float* imgf  = (const float*)d_in[0];
    const float* attrs = (const float*)d_in[1];
    const float* attg  = (const float*)d_in[3];
    const float* imgw  = (const float*)d_in[4];
    const float* semw  = (const float*)d_in[5];
    const float* semb  = (const float*)d_in[6];
    const float* fcw   = (const float*)d_in[7];
    const float* fcb   = (const float*)d_in[8];
    float* out = (float*)d_out;

    char* ws = (char*)d_ws;
    size_t off = 0;
    auto alloc = [&](size_t b) { size_t o = off; off = (off + b + 255) & ~(size_t)255; return o; };
    float* gpart          = (float*)(ws + alloc((size_t)8 * 512 * 256 * 4));      // 4.19 MB
    unsigned short* gn_bf = (unsigned short*)(ws + alloc((size_t)500 * 256 * 2));
    float* sim            = (float*)(ws + alloc((size_t)CLS * CLS * 4));          // 1 MB
    unsigned short* imgH  = (unsigned short*)(ws + alloc((size_t)256 * 1024 * 2));      // 0.5 MB
    unsigned short* asem  = (unsigned short*)(ws + alloc((size_t)512 * 1024 * 2));      // 1 MB
    float* outP           = (float*)(ws + alloc((size_t)32 * BATCH * CLS * 4));   // 16.4 MB

    // N1: g partials + imgH + asem, one dispatch (224 blocks)
    mega_gemm<<<224, 256, 0, stream>>>(attrs, attg, imgf, imgw, semw,
                                       gpart, imgH, asem);
    // N2: reduce 8 partials + row-normalize -> gn bf16
    reduce_norm_kernel<<<CLS, 256, 0, stream>>>(gpart, gn_bf);
    // N3: sim = gn @ gn^T [500,500] f32
    sim_kernel<<<dim3(8, 4), 256, 0, stream>>>(gn_bf, sim);
    // N4: fused softmax-gather + relu-reduction -> outP[32][256][500]
    fused_sg<<<dim3(4, 8, 32), 256, 0, stream>>>(sim, imgH, asem, semb, fcw, outP);
    // N5: finalize (32 partials)
    finalize_kernel<<<(BATCH * CLS + 255) / 256, 256, 0, stream>>>(outP, fcb, out);
}

// Round 17
// 87.476 us; speedup vs baseline: 1.8140x; 1.8140x over previous
//
#include <hip/hip_runtime.h>
#include <math.h>

#define BATCH 256
#define CLS 500
#define T_TEMP_ 10.0f
#define THRESH_ 0.86602540378443864676f
#define NEGV -9.0e15f

typedef __attribute__((ext_vector_type(8))) short short8;
typedef __attribute__((ext_vector_type(8))) unsigned short u16x8;
typedef __attribute__((ext_vector_type(4))) unsigned short u16x4;
typedef __attribute__((ext_vector_type(4))) float f32x4;

static __device__ __forceinline__ unsigned short f2bf(float x) {
    unsigned int u = __builtin_bit_cast(unsigned int, x);
    u += 0x7fff + ((u >> 16) & 1);
    return (unsigned short)(u >> 16);
}
static __device__ __forceinline__ float bf2f(unsigned short v) {
    return __builtin_bit_cast(float, (unsigned int)v << 16);
}
static __device__ __forceinline__ float fel(const float4& v, int j) { return (&v.x)[j]; }
static __device__ __forceinline__ u16x8 pack8(const float4& a, const float4& b) {
    u16x8 o;
    o[0] = f2bf(a.x); o[1] = f2bf(a.y); o[2] = f2bf(a.z); o[3] = f2bf(a.w);
    o[4] = f2bf(b.x); o[5] = f2bf(b.y); o[6] = f2bf(b.z); o[7] = f2bf(b.w);
    return o;
}

// =============== N1: mega-GEMM v2 (r16-verified, verbatim) ===============
// bid [0,128):   G: gpart[8][512][256] f32 = split-K8 partials of attrs@attg
// bid [128,160): I: imgH[256][1024] bf16 = imgf@imgw, full K
// bid [160,224): S: asem[512][1024] bf16 = attrs@semw, full K
__global__ __launch_bounds__(256) void mega_gemm(
    const float* __restrict__ attrs, const float* __restrict__ attg,
    const float* __restrict__ imgf, const float* __restrict__ imgw,
    const float* __restrict__ semw,
    float* __restrict__ gpart, unsigned short* __restrict__ imgH,
    unsigned short* __restrict__ asem)
{
    __shared__ unsigned short As[64][40];
    __shared__ unsigned short Bs[128][40];
    const int t = threadIdx.x;
    const int bid = blockIdx.x;

    const int w = t >> 6, lane = t & 63;
    const int wr = w >> 1, wc = w & 1;
    const int fr = lane & 15, kg = lane >> 4;
    const int as_row = t >> 2, as_kq = t & 3;
    const int bs_nc = (t & 31) * 4, bs_kr = t >> 5;

    const float* A; const float* Bf;
    int ar0, alim, n0, k0, klen, bstride, split = 0;
    if (bid < 128) {
        const int mt = bid >> 4, nt = (bid >> 3) & 1; split = bid & 7;
        A = attrs; alim = CLS; ar0 = mt * 64;
        Bf = attg; bstride = 256; n0 = nt * 128;
        k0 = split * 128; klen = 128;
    } else if (bid < 160) {
        const int idx = bid - 128;
        const int mt = idx >> 3, nt = idx & 7;
        A = imgf; alim = 256; ar0 = mt * 64;
        Bf = imgw; bstride = 1024; n0 = nt * 128;
        k0 = 0; klen = 1024;
    } else {
        const int idx = bid - 160;
        const int mt = idx >> 3, nt = idx & 7;
        A = attrs; alim = CLS; ar0 = mt * 64;
        Bf = semw; bstride = 1024; n0 = nt * 128;
        k0 = 0; klen = 1024;
    }

    f32x4 acc[2][4];
    #pragma unroll
    for (int i = 0; i < 2; ++i)
        #pragma unroll
        for (int j = 0; j < 4; ++j) acc[i][j] = (f32x4){0.f, 0.f, 0.f, 0.f};

    for (int kb = k0; kb < k0 + klen; kb += 32) {
        {
            const int gr = ar0 + as_row;
            float4 v0 = make_float4(0.f,0.f,0.f,0.f), v1 = v0;
            if (gr < alim) {
                const float* ap = &A[(size_t)gr * 1024 + kb + as_kq * 8];
                v0 = *(const float4*)ap; v1 = *(const float4*)(ap + 4);
            }
            *(u16x8*)&As[as_row][as_kq * 8] = pack8(v0, v1);
        }
        {
            const float* bp = &Bf[(size_t)(kb + bs_kr * 4) * bstride + n0 + bs_nc];
            float4 r0 = *(const float4*)(bp);
            float4 r1 = *(const float4*)(bp + bstride);
            float4 r2 = *(const float4*)(bp + 2 * bstride);
            float4 r3 = *(const float4*)(bp + 3 * bstride);
            #pragma unroll
            for (int j = 0; j < 4; ++j) {
                unsigned int lo = (unsigned int)f2bf(fel(r0, j)) | ((unsigned int)f2bf(fel(r1, j)) << 16);
                unsigned int hi = (unsigned int)f2bf(fel(r2, j)) | ((unsigned int)f2bf(fel(r3, j)) << 16);
                uint2 u2; u2.x = lo; u2.y = hi;
                *(uint2*)&Bs[bs_nc + j][bs_kr * 4] = u2;
            }
        }
        __syncthreads();
        short8 af[2], bfr[4];
        #pragma unroll
        for (int i = 0; i < 2; ++i) af[i] = *(short8*)&As[wr * 32 + i * 16 + fr][kg * 8];
        #pragma unroll
        for (int j = 0; j < 4; ++j) bfr[j] = *(short8*)&Bs[wc * 64 + j * 16 + fr][kg * 8];
        #pragma unroll
        for (int i = 0; i < 2; ++i)
            #pragma unroll
            for (int j = 0; j < 4; ++j)
                acc[i][j] = __builtin_amdgcn_mfma_f32_16x16x32_bf16(af[i], bfr[j], acc[i][j], 0, 0, 0);
        __syncthreads();
    }

    const int orow0 = ar0 + wr * 32, ocol0 = n0 + wc * 64;
    if (bid < 128) {
        float* Gp = gpart + (size_t)split * (512 * 256);
        #pragma unroll
        for (int i = 0; i < 2; ++i) {
            const int r0 = orow0 + i * 16 + kg * 4;
            #pragma unroll
            for (int j = 0; j < 4; ++j) {
                const int cc = ocol0 + j * 16 + fr;
                #pragma unroll
                for (int r = 0; r < 4; ++r)
                    Gp[(size_t)(r0 + r) * 256 + cc] = acc[i][j][r];
            }
        }
    } else {
        unsigned short* Cw = (bid < 160) ? imgH : asem;
        #pragma unroll
        for (int i = 0; i < 2; ++i) {
            const int r0 = orow0 + i * 16 + kg * 4;
            #pragma unroll
            for (int j = 0; j < 4; ++j) {
                const int cc = ocol0 + j * 16 + fr;
                #pragma unroll
                for (int r = 0; r < 4; ++r)
                    Cw[(size_t)(r0 + r) * 1024 + cc] = f2bf(acc[i][j][r]);
            }
        }
    }
}

// =============== N2: reduce 8 partials + row-normalize -> gn bf16 (verified, verbatim) ===============
__global__ __launch_bounds__(256) void reduce_norm_kernel(
    const float* __restrict__ part, unsigned short* __restrict__ gn_bf)
{
    const int c = blockIdx.x, t = threadIdx.x;
    float v = 0.f;
    #pragma unroll
    for (int z = 0; z < 8; ++z) v += part[(size_t)z * (512 * 256) + c * 256 + t];
    float ss = v * v;
    #pragma unroll
    for (int off = 32; off >= 1; off >>= 1) ss += __shfl_down(ss, off);
    __shared__ float red[4];
    const int wave = t >> 6, lane = t & 63;
    if (lane == 0) red[wave] = ss;
    __syncthreads();
    const float tot = red[0] + red[1] + red[2] + red[3];
    const float rn  = 1.f / sqrtf(tot);
    gn_bf[c * 256 + t] = f2bf(v * rn);
}

// =============== N3: sim = gn @ gn^T (verified, verbatim) ===============
__global__ __launch_bounds__(256) void sim_kernel(
    const unsigned short* __restrict__ gn, float* __restrict__ S)
{
    __shared__ unsigned short As[64][40];
    __shared__ unsigned short Bs[128][40];
    const int t  = threadIdx.x;
    const int ar0 = blockIdx.x * 64;
    const int n0  = blockIdx.y * 128;

    const int w = t >> 6, lane = t & 63;
    const int wr = w >> 1, wc = w & 1;
    const int fr = lane & 15, kg = lane >> 4;
    const int a_row = t >> 2, a_k = (t & 3) * 8;
    const int b_row = t >> 1, b_k = (t & 1) * 16;
    const int gra = ar0 + a_row;
    const int grb = n0 + b_row;
    const bool va = gra < CLS;
    const bool vb = grb < CLS;
    const size_t abase = (size_t)gra * 256 + a_k;
    const size_t bbase = (size_t)grb * 256 + b_k;

    u16x8 zz = {0,0,0,0,0,0,0,0};
    u16x8 pa = zz, pb0 = zz, pb1 = zz;
    if (va) pa = *(const u16x8*)&gn[abase];
    if (vb) { pb0 = *(const u16x8*)&gn[bbase]; pb1 = *(const u16x8*)&gn[bbase + 8]; }

    f32x4 acc[2][4];
    #pragma unroll
    for (int i = 0; i < 2; ++i)
        #pragma unroll
        for (int j = 0; j < 4; ++j) acc[i][j] = (f32x4){0.f, 0.f, 0.f, 0.f};

    for (int kb = 0; kb < 256; kb += 32) {
        *(u16x8*)&As[a_row][a_k] = pa;
        *(u16x8*)&Bs[b_row][b_k] = pb0;
        *(u16x8*)&Bs[b_row][b_k + 8] = pb1;
        __syncthreads();

        const int kn = kb + 32;
        if (kn < 256) {
            if (va) pa = *(const u16x8*)&gn[abase + kn];
            if (vb) { pb0 = *(const u16x8*)&gn[bbase + kn]; pb1 = *(const u16x8*)&gn[bbase + kn + 8]; }
        }

        short8 af[2], bfr[4];
        #pragma unroll
        for (int i = 0; i < 2; ++i) af[i] = *(short8*)&As[wr * 32 + i * 16 + fr][kg * 8];
        #pragma unroll
        for (int j = 0; j < 4; ++j) bfr[j] = *(short8*)&Bs[wc * 64 + j * 16 + fr][kg * 8];
        #pragma unroll
        for (int i = 0; i < 2; ++i)
            #pragma unroll
            for (int j = 0; j < 4; ++j)
                acc[i][j] = __builtin_amdgcn_mfma_f32_16x16x32_bf16(af[i], bfr[j], acc[i][j], 0, 0, 0);
        __syncthreads();
    }

    const int orow0 = ar0 + wr * 32, ocol0 = n0 + wc * 64;
    #pragma unroll
    for (int i = 0; i < 2; ++i) {
        const int r0 = orow0 + i * 16 + kg * 4;
        #pragma unroll
        for (int j = 0; j < 4; ++j) {
            const int cc = ocol0 + j * 16 + fr;
            if (cc >= CLS) continue;
            #pragma unroll
            for (int r = 0; r < 4; ++r) {
                const int rr = r0 + r;
                if (rr < CLS) S[(size_t)rr * CLS + cc] = acc[i][j][r];
            }
        }
    }
}

// =============== N4: colout — softmax(row c) once + sem gather + column sweep -> out ===============
// One block per class c (500 blocks). Phase A: r14-verified softmax weights.
// Phase B: r16-verified asem gather (+semb) -> sems LDS. Phase C: sweep 256 batch rows,
// imgH staged via LDS in 64-h chunks (coalesced; imgH is L2-resident).
__global__ __launch_bounds__(256) void colout_kernel(
    const float* __restrict__ sim, const unsigned short* __restrict__ asem,
    const unsigned short* __restrict__ imgH, const float* __restrict__ semb,
    const float* __restrict__ fcw, const float* __restrict__ fcb,
    float* __restrict__ out)
{
    __shared__ float p_s[512];
    __shared__ float redm[4];
    __shared__ float reds[4];
    __shared__ float sems[1024];
    __shared__ float imgs[256][67];   // 64-h chunk, pad 67 (2-way max on lane reads)

    const int c = blockIdx.x, t = threadIdx.x;
    const int wave = t >> 6, lane = t & 63;

    // ---- phase A: softmax weights (r14-verified pattern) ----
    const float d0 = sim[(size_t)c * CLS + t];
    const float d1 = (t + 256 < CLS) ? sim[(size_t)c * CLS + t + 256] : NEGV;

    float vmax = fmaxf((d0 > THRESH_) ? d0 : NEGV, (d1 > THRESH_) ? d1 : NEGV);
    #pragma unroll
    for (int off = 32; off >= 1; off >>= 1) vmax = fmaxf(vmax, __shfl_down(vmax, off));
    if (lane == 0) redm[wave] = vmax;
    __syncthreads();
    const float m = fmaxf(fmaxf(redm[0], redm[1]), fmaxf(redm[2], redm[3]));

    const float p0 = (d0 > THRESH_) ? expf(T_TEMP_ * (d0 - m)) : 0.f;
    const float p1 = (d1 > THRESH_) ? expf(T_TEMP_ * (d1 - m)) : 0.f;
    p_s[t] = p0;
    p_s[t + 256] = p1;
    float vsum = p0 + p1;
    #pragma unroll
    for (int off = 32; off >= 1; off >>= 1) vsum += __shfl_down(vsum, off);
    if (lane == 0) reds[wave] = vsum;
    __syncthreads();
    const float inv = 1.f / (reds[0] + reds[1] + reds[2] + reds[3]);

    // ---- phase B: gather asem rows (+semb) -> sems (r16-verified pattern) ----
    float acc[4] = {0.f, 0.f, 0.f, 0.f};
    for (int base = 0; base < 512; base += 64) {
        const float pv_l = p_s[base + lane];
        unsigned long long mask = __ballot(pv_l > 0.f);
        while (mask) {
            const int l = __ffsll((long long)mask) - 1;
            mask &= mask - 1;
            const int c2 = base + l;
            const float pv = p_s[c2];
            const unsigned short* ar = &asem[(size_t)c2 * 1024 + t];
            #pragma unroll
            for (int j = 0; j < 4; ++j) acc[j] += pv * bf2f(ar[256 * j]);
        }
    }
    #pragma unroll
    for (int j = 0; j < 4; ++j)
        sems[t + 256 * j] = acc[j] * inv + semb[t + 256 * j];
    __syncthreads();

    // ---- phase C: sweep all 256 batch rows in 64-h chunks ----
    float oacc = 0.f;
    for (int hc = 0; hc < 16; ++hc) {
        #pragma unroll
        for (int it = 0; it < 16; ++it) {
            const int row = it * 16 + (t >> 4);
            const int col = (t & 15) * 4;
            u16x4 v = *(const u16x4*)&imgH[(size_t)row * 1024 + hc * 64 + col];
            imgs[row][col + 0] = bf2f(v[0]);
            imgs[row][col + 1] = bf2f(v[1]);
            imgs[row][col + 2] = bf2f(v[2]);
            imgs[row][col + 3] = bf2f(v[3]);
        }
        __syncthreads();
        const float* sp = &sems[hc * 64];
        const float* fp = &fcw[hc * 64];
        #pragma unroll
        for (int h = 0; h < 64; ++h)
            oacc += fmaxf(imgs[t][h] + sp[h], 0.f) * fp[h];
        __syncthreads();
    }
    out[(size_t)t * CLS + c] = oacc + fcb[0];
}

extern "C" void kernel_launch(void* const* d_in, const int* in_sizes, int n_in,
                              void* d_out, int out_size, void* d_ws, size_t ws_size,
                              hipStream_t stream)
{
    const float* imgf  = (const float*)d_in[0];
    const float* attrs = (const float*)d_in[1];
    const float* attg  = (const float*)d_in[3];
    const float* imgw  = (const float*)d_in[4];
    const float* semw  = (const float*)d_in[5];
    const float* semb  = (const float*)d_in[6];
    const float* fcw   = (const float*)d_in[7];
    const float* fcb   = (const float*)d_in[8];
    float* out = (float*)d_out;

    char* ws = (char*)d_ws;
    size_t off = 0;
    auto alloc = [&](size_t b) { size_t o = off; off = (off + b + 255) & ~(size_t)255; return o; };
    float* gpart          = (float*)(ws + alloc((size_t)8 * 512 * 256 * 4));      // 4.19 MB
    unsigned short* gn_bf = (unsigned short*)(ws + alloc((size_t)500 * 256 * 2));
    float* sim            = (float*)(ws + alloc((size_t)CLS * CLS * 4));          // 1 MB
    unsigned short* imgH  = (unsigned short*)(ws + alloc((size_t)256 * 1024 * 2));      // 0.5 MB
    unsigned short* asem  = (unsigned short*)(ws + alloc((size_t)512 * 1024 * 2));      // 1 MB

    // N1: g partials + imgH + asem, one dispatch (224 blocks)
    mega_gemm<<<224, 256, 0, stream>>>(attrs, attg, imgf, imgw, semw,
                                       gpart, imgH, asem);
    // N2: reduce 8 partials + row-normalize -> gn bf16
    reduce_norm_kernel<<<CLS, 256, 0, stream>>>(gpart, gn_bf);
    // N3: sim = gn @ gn^T [500,500] f32
    sim_kernel<<<dim3(8, 4), 256, 0, stream>>>(gn_bf, sim);
    // N4: per-class softmax + gather + batch sweep -> out directly
    colout_kernel<<<CLS, 256, 0, stream>>>(sim, asem, imgH, semb, fcw, fcb, out);
}

// Round 19
// 78.184 us; speedup vs baseline: 2.0296x; 1.1189x over previous
//
#include <hip/hip_runtime.h>
#include <math.h>

#define BATCH 256
#define CLS 500
#define T_TEMP_ 10.0f
#define THRESH_ 0.86602540378443864676f
#define NEGV -9.0e15f

typedef __attribute__((ext_vector_type(8))) short short8;
typedef __attribute__((ext_vector_type(8))) unsigned short u16x8;
typedef __attribute__((ext_vector_type(4))) unsigned short u16x4;
typedef __attribute__((ext_vector_type(4))) float f32x4;

static __device__ __forceinline__ unsigned short f2bf(float x) {
    unsigned int u = __builtin_bit_cast(unsigned int, x);
    u += 0x7fff + ((u >> 16) & 1);
    return (unsigned short)(u >> 16);
}
static __device__ __forceinline__ float bf2f(unsigned short v) {
    return __builtin_bit_cast(float, (unsigned int)v << 16);
}
static __device__ __forceinline__ float fel(const float4& v, int j) { return (&v.x)[j]; }
static __device__ __forceinline__ u16x8 pack8(const float4& a, const float4& b) {
    u16x8 o;
    o[0] = f2bf(a.x); o[1] = f2bf(a.y); o[2] = f2bf(a.z); o[3] = f2bf(a.w);
    o[4] = f2bf(b.x); o[5] = f2bf(b.y); o[6] = f2bf(b.z); o[7] = f2bf(b.w);
    return o;
}

// =============== N1: mega-GEMM v2 (r17-verified, verbatim — no prefetch, imgH row-major) ===============
// bid [0,128):   G: gpart[8][512][256] f32 = split-K8 partials of attrs@attg
// bid [128,160): I: imgH[256][1024] bf16 = imgf@imgw, full K
// bid [160,224): S: asem[512][1024] bf16 = attrs@semw, full K
__global__ __launch_bounds__(256) void mega_gemm(
    const float* __restrict__ attrs, const float* __restrict__ attg,
    const float* __restrict__ imgf, const float* __restrict__ imgw,
    const float* __restrict__ semw,
    float* __restrict__ gpart, unsigned short* __restrict__ imgH,
    unsigned short* __restrict__ asem)
{
    __shared__ unsigned short As[64][40];
    __shared__ unsigned short Bs[128][40];
    const int t = threadIdx.x;
    const int bid = blockIdx.x;

    const int w = t >> 6, lane = t & 63;
    const int wr = w >> 1, wc = w & 1;
    const int fr = lane & 15, kg = lane >> 4;
    const int as_row = t >> 2, as_kq = t & 3;
    const int bs_nc = (t & 31) * 4, bs_kr = t >> 5;

    const float* A; const float* Bf;
    int ar0, alim, n0, k0, klen, bstride, split = 0;
    if (bid < 128) {
        const int mt = bid >> 4, nt = (bid >> 3) & 1; split = bid & 7;
        A = attrs; alim = CLS; ar0 = mt * 64;
        Bf = attg; bstride = 256; n0 = nt * 128;
        k0 = split * 128; klen = 128;
    } else if (bid < 160) {
        const int idx = bid - 128;
        const int mt = idx >> 3, nt = idx & 7;
        A = imgf; alim = 256; ar0 = mt * 64;
        Bf = imgw; bstride = 1024; n0 = nt * 128;
        k0 = 0; klen = 1024;
    } else {
        const int idx = bid - 160;
        const int mt = idx >> 3, nt = idx & 7;
        A = attrs; alim = CLS; ar0 = mt * 64;
        Bf = semw; bstride = 1024; n0 = nt * 128;
        k0 = 0; klen = 1024;
    }

    f32x4 acc[2][4];
    #pragma unroll
    for (int i = 0; i < 2; ++i)
        #pragma unroll
        for (int j = 0; j < 4; ++j) acc[i][j] = (f32x4){0.f, 0.f, 0.f, 0.f};

    for (int kb = k0; kb < k0 + klen; kb += 32) {
        {
            const int gr = ar0 + as_row;
            float4 v0 = make_float4(0.f,0.f,0.f,0.f), v1 = v0;
            if (gr < alim) {
                const float* ap = &A[(size_t)gr * 1024 + kb + as_kq * 8];
                v0 = *(const float4*)ap; v1 = *(const float4*)(ap + 4);
            }
            *(u16x8*)&As[as_row][as_kq * 8] = pack8(v0, v1);
        }
        {
            const float* bp = &Bf[(size_t)(kb + bs_kr * 4) * bstride + n0 + bs_nc];
            float4 r0 = *(const float4*)(bp);
            float4 r1 = *(const float4*)(bp + bstride);
            float4 r2 = *(const float4*)(bp + 2 * bstride);
            float4 r3 = *(const float4*)(bp + 3 * bstride);
            #pragma unroll
            for (int j = 0; j < 4; ++j) {
                unsigned int lo = (unsigned int)f2bf(fel(r0, j)) | ((unsigned int)f2bf(fel(r1, j)) << 16);
                unsigned int hi = (unsigned int)f2bf(fel(r2, j)) | ((unsigned int)f2bf(fel(r3, j)) << 16);
                uint2 u2; u2.x = lo; u2.y = hi;
                *(uint2*)&Bs[bs_nc + j][bs_kr * 4] = u2;
            }
        }
        __syncthreads();
        short8 af[2], bfr[4];
        #pragma unroll
        for (int i = 0; i < 2; ++i) af[i] = *(short8*)&As[wr * 32 + i * 16 + fr][kg * 8];
        #pragma unroll
        for (int j = 0; j < 4; ++j) bfr[j] = *(short8*)&Bs[wc * 64 + j * 16 + fr][kg * 8];
        #pragma unroll
        for (int i = 0; i < 2; ++i)
            #pragma unroll
            for (int j = 0; j < 4; ++j)
                acc[i][j] = __builtin_amdgcn_mfma_f32_16x16x32_bf16(af[i], bfr[j], acc[i][j], 0, 0, 0);
        __syncthreads();
    }

    const int orow0 = ar0 + wr * 32, ocol0 = n0 + wc * 64;
    if (bid < 128) {
        float* Gp = gpart + (size_t)split * (512 * 256);
        #pragma unroll
        for (int i = 0; i < 2; ++i) {
            const int r0 = orow0 + i * 16 + kg * 4;
            #pragma unroll
            for (int j = 0; j < 4; ++j) {
                const int cc = ocol0 + j * 16 + fr;
                #pragma unroll
                for (int r = 0; r < 4; ++r)
                    Gp[(size_t)(r0 + r) * 256 + cc] = acc[i][j][r];
            }
        }
    } else {
        unsigned short* Cw = (bid < 160) ? imgH : asem;
        #pragma unroll
        for (int i = 0; i < 2; ++i) {
            const int r0 = orow0 + i * 16 + kg * 4;
            #pragma unroll
            for (int j = 0; j < 4; ++j) {
                const int cc = ocol0 + j * 16 + fr;
                #pragma unroll
                for (int r = 0; r < 4; ++r)
                    Cw[(size_t)(r0 + r) * 1024 + cc] = f2bf(acc[i][j][r]);
            }
        }
    }
}

// =============== N2: reduce 8 partials + row-normalize -> gn bf16 (verified, verbatim) ===============
__global__ __launch_bounds__(256) void reduce_norm_kernel(
    const float* __restrict__ part, unsigned short* __restrict__ gn_bf)
{
    const int c = blockIdx.x, t = threadIdx.x;
    float v = 0.f;
    #pragma unroll
    for (int z = 0; z < 8; ++z) v += part[(size_t)z * (512 * 256) + c * 256 + t];
    float ss = v * v;
    #pragma unroll
    for (int off = 32; off >= 1; off >>= 1) ss += __shfl_down(ss, off);
    __shared__ float red[4];
    const int wave = t >> 6, lane = t & 63;
    if (lane == 0) red[wave] = ss;
    __syncthreads();
    const float tot = red[0] + red[1] + red[2] + red[3];
    const float rn  = 1.f / sqrtf(tot);
    gn_bf[c * 256 + t] = f2bf(v * rn);
}

// =============== N3: sim = gn @ gn^T (verified, verbatim) ===============
__global__ __launch_bounds__(256) void sim_kernel(
    const unsigned short* __restrict__ gn, float* __restrict__ S)
{
    __shared__ unsigned short As[64][40];
    __shared__ unsigned short Bs[128][40];
    const int t  = threadIdx.x;
    const int ar0 = blockIdx.x * 64;
    const int n0  = blockIdx.y * 128;

    const int w = t >> 6, lane = t & 63;
    const int wr = w >> 1, wc = w & 1;
    const int fr = lane & 15, kg = lane >> 4;
    const int a_row = t >> 2, a_k = (t & 3) * 8;
    const int b_row = t >> 1, b_k = (t & 1) * 16;
    const int gra = ar0 + a_row;
    const int grb = n0 + b_row;
    const bool va = gra < CLS;
    const bool vb = grb < CLS;
    const size_t abase = (size_t)gra * 256 + a_k;
    const size_t bbase = (size_t)grb * 256 + b_k;

    u16x8 zz = {0,0,0,0,0,0,0,0};
    u16x8 pa = zz, pb0 = zz, pb1 = zz;
    if (va) pa = *(const u16x8*)&gn[abase];
    if (vb) { pb0 = *(const u16x8*)&gn[bbase]; pb1 = *(const u16x8*)&gn[bbase + 8]; }

    f32x4 acc[2][4];
    #pragma unroll
    for (int i = 0; i < 2; ++i)
        #pragma unroll
        for (int j = 0; j < 4; ++j) acc[i][j] = (f32x4){0.f, 0.f, 0.f, 0.f};

    for (int kb = 0; kb < 256; kb += 32) {
        *(u16x8*)&As[a_row][a_k] = pa;
        *(u16x8*)&Bs[b_row][b_k] = pb0;
        *(u16x8*)&Bs[b_row][b_k + 8] = pb1;
        __syncthreads();

        const int kn = kb + 32;
        if (kn < 256) {
            if (va) pa = *(const u16x8*)&gn[abase + kn];
            if (vb) { pb0 = *(const u16x8*)&gn[bbase + kn]; pb1 = *(const u16x8*)&gn[bbase + kn + 8]; }
        }

        short8 af[2], bfr[4];
        #pragma unroll
        for (int i = 0; i < 2; ++i) af[i] = *(short8*)&As[wr * 32 + i * 16 + fr][kg * 8];
        #pragma unroll
        for (int j = 0; j < 4; ++j) bfr[j] = *(short8*)&Bs[wc * 64 + j * 16 + fr][kg * 8];
        #pragma unroll
        for (int i = 0; i < 2; ++i)
            #pragma unroll
            for (int j = 0; j < 4; ++j)
                acc[i][j] = __builtin_amdgcn_mfma_f32_16x16x32_bf16(af[i], bfr[j], acc[i][j], 0, 0, 0);
        __syncthreads();
    }

    const int orow0 = ar0 + wr * 32, ocol0 = n0 + wc * 64;
    #pragma unroll
    for (int i = 0; i < 2; ++i) {
        const int r0 = orow0 + i * 16 + kg * 4;
        #pragma unroll
        for (int j = 0; j < 4; ++j) {
            const int cc = ocol0 + j * 16 + fr;
            if (cc >= CLS) continue;
            #pragma unroll
            for (int r = 0; r < 4; ++r) {
                const int rr = r0 + r;
                if (rr < CLS) S[(size_t)rr * CLS + cc] = acc[i][j][r];
            }
        }
    }
}

// =============== N4: colout v3 — softmax + gather (r17-verified verbatim) + streaming sweep ===============
// One block per class c. Phase C: thread t owns batch row t; streams imgH row t
// (u16x8 global loads, per-thread sequential, L2-resident); sems/fcw uniform reads.
// Same h-summation order as r17 -> bit-identical output.
__global__ __launch_bounds__(256) void colout_kernel(
    const float* __restrict__ sim, const unsigned short* __restrict__ asem,
    const unsigned short* __restrict__ imgH, const float* __restrict__ semb,
    const float* __restrict__ fcw, const float* __restrict__ fcb,
    float* __restrict__ out)
{
    __shared__ float p_s[512];
    __shared__ float redm[4];
    __shared__ float reds[4];
    __shared__ float sems[1024];

    const int c = blockIdx.x, t = threadIdx.x;
    const int wave = t >> 6, lane = t & 63;

    // ---- phase A: softmax weights (r17-verified, verbatim) ----
    const float d0 = sim[(size_t)c * CLS + t];
    const float d1 = (t + 256 < CLS) ? sim[(size_t)c * CLS + t + 256] : NEGV;

    float vmax = fmaxf((d0 > THRESH_) ? d0 : NEGV, (d1 > THRESH_) ? d1 : NEGV);
    #pragma unroll
    for (int off = 32; off >= 1; off >>= 1) vmax = fmaxf(vmax, __shfl_down(vmax, off));
    if (lane == 0) redm[wave] = vmax;
    __syncthreads();
    const float m = fmaxf(fmaxf(redm[0], redm[1]), fmaxf(redm[2], redm[3]));

    const float p0 = (d0 > THRESH_) ? expf(T_TEMP_ * (d0 - m)) : 0.f;
    const float p1 = (d1 > THRESH_) ? expf(T_TEMP_ * (d1 - m)) : 0.f;
    p_s[t] = p0;
    p_s[t + 256] = p1;
    float vsum = p0 + p1;
    #pragma unroll
    for (int off = 32; off >= 1; off >>= 1) vsum += __shfl_down(vsum, off);
    if (lane == 0) reds[wave] = vsum;
    __syncthreads();
    const float inv = 1.f / (reds[0] + reds[1] + reds[2] + reds[3]);

    // ---- phase B: gather asem rows (+semb) -> sems (r17-verified, verbatim) ----
    float acc[4] = {0.f, 0.f, 0.f, 0.f};
    for (int base = 0; base < 512; base += 64) {
        const float pv_l = p_s[base + lane];
        unsigned long long mask = __ballot(pv_l > 0.f);
        while (mask) {
            const int l = __ffsll((long long)mask) - 1;
            mask &= mask - 1;
            const int c2 = base + l;
            const float pv = p_s[c2];
            const unsigned short* ar = &asem[(size_t)c2 * 1024 + t];
            #pragma unroll
            for (int j = 0; j < 4; ++j) acc[j] += pv * bf2f(ar[256 * j]);
        }
    }
    #pragma unroll
    for (int j = 0; j < 4; ++j)
        sems[t + 256 * j] = acc[j] * inv + semb[t + 256 * j];
    __syncthreads();

    // ---- phase C: per-thread row streaming (no LDS staging, no transpose) ----
    float oacc = 0.f;
    const unsigned short* ip = &imgH[(size_t)t * 1024];
    #pragma unroll 4
    for (int hq = 0; hq < 128; ++hq) {
        const u16x8 v = *(const u16x8*)&ip[hq * 8];
        const f32x4 s0 = *(const f32x4*)&sems[hq * 8];       // uniform broadcast
        const f32x4 s1 = *(const f32x4*)&sems[hq * 8 + 4];
        const f32x4 f0 = *(const f32x4*)&fcw[hq * 8];        // uniform global
        const f32x4 f1 = *(const f32x4*)&fcw[hq * 8 + 4];
        oacc += fmaxf(bf2f(v[0]) + s0[0], 0.f) * f0[0];
        oacc += fmaxf(bf2f(v[1]) + s0[1], 0.f) * f0[1];
        oacc += fmaxf(bf2f(v[2]) + s0[2], 0.f) * f0[2];
        oacc += fmaxf(bf2f(v[3]) + s0[3], 0.f) * f0[3];
        oacc += fmaxf(bf2f(v[4]) + s1[0], 0.f) * f1[0];
        oacc += fmaxf(bf2f(v[5]) + s1[1], 0.f) * f1[1];
        oacc += fmaxf(bf2f(v[6]) + s1[2], 0.f) * f1[2];
        oacc += fmaxf(bf2f(v[7]) + s1[3], 0.f) * f1[3];
    }
    out[(size_t)t * CLS + c] = oacc + fcb[0];
}

extern "C" void kernel_launch(void* const* d_in, const int* in_sizes, int n_in,
                              void* d_out, int out_size, void* d_ws, size_t ws_size,
                              hipStream_t stream)
{
    const float* imgf  = (const float*)d_in[0];
    const float* attrs = (const float*)d_in[1];
    const float* attg  = (const float*)d_in[3];
    const float* imgw  = (const float*)d_in[4];
    const float* semw  = (const float*)d_in[5];
    const float* semb  = (const float*)d_in[6];
    const float* fcw   = (const float*)d_in[7];
    const float* fcb   = (const float*)d_in[8];
    float* out = (float*)d_out;

    char* ws = (char*)d_ws;
    size_t off = 0;
    auto alloc = [&](size_t b) { size_t o = off; off = (off + b + 255) & ~(size_t)255; return o; };
    float* gpart          = (float*)(ws + alloc((size_t)8 * 512 * 256 * 4));      // 4.19 MB
    unsigned short* gn_bf = (unsigned short*)(ws + alloc((size_t)500 * 256 * 2));
    float* sim            = (float*)(ws + alloc((size_t)CLS * CLS * 4));          // 1 MB
    unsigned short* imgH  = (unsigned short*)(ws + alloc((size_t)256 * 1024 * 2));      // 0.5 MB
    unsigned short* asem  = (unsigned short*)(ws + alloc((size_t)512 * 1024 * 2));      // 1 MB

    // N1: g partials + imgH + asem, one dispatch (224 blocks)
    mega_gemm<<<224, 256, 0, stream>>>(attrs, attg, imgf, imgw, semw,
                                       gpart, imgH, asem);
    // N2: reduce 8 partials + row-normalize -> gn bf16
    reduce_norm_kernel<<<CLS, 256, 0, stream>>>(gpart, gn_bf);
    // N3: sim = gn @ gn^T [500,500] f32
    sim_kernel<<<dim3(8, 4), 256, 0, stream>>>(gn_bf, sim);
    // N4: per-class softmax + gather + streaming batch sweep -> out
    colout_kernel<<<CLS, 256, 0, stream>>>(sim, asem, imgH, semb, fcw, fcb, out);
}